// Round 2
// 420.033 us; speedup vs baseline: 1.0474x; 1.0474x over previous
//
#include <hip/hip_runtime.h>
#include <hip/hip_bf16.h>

// MoE top-2, d=1024, E=8, N=8192 tokens. Grouped-GEMM design:
//   gate(top2 + x->bf16 cast) -> plan -> fill -> GEMM1(relu) -> GEMM2(+atomic combine)
// R1: gate rewrite. R3: coalesced chunked DMA staging. R4: BK=32 double-buffer,
//     raw s_barrier + vmcnt(4).
// R5: 3-buffer depth-2 pipeline (vmcnt(8)) + XCD tile swizzle. FAILED correctness:
//     raw s_barrier/s_waitcnt builtins are IntrNoMem -> scheduler moved ds_read/MFMA
//     across them (rule #18 failure mode), racing the in-flight DMA.
// R6: same pipeline, FENCED: sched_barrier(0) after vmcnt+barrier (no ds_read hoist)
//     and after the MFMA cluster, + s_waitcnt lgkmcnt(0) before the end barrier
//     (ds_reads retired before the buffer is republished).

#define NTOK   8192
#define DM     1024
#define NE     8
#define BM     128
#define NSLOT  (NTOK * 2)
#define PADCAP (NSLOT + NE * BM)      // 17408
#define MAXTILES (PADCAP / BM)        // 136

typedef __attribute__((ext_vector_type(8))) short  bf16x8;
typedef __attribute__((ext_vector_type(4))) float  f32x4;
typedef __attribute__((ext_vector_type(8))) unsigned short u16x8;

__device__ __forceinline__ unsigned short f2bf(float f) {
    union { float f; unsigned u; } v; v.f = f;
    unsigned r = v.u + 0x7fffu + ((v.u >> 16) & 1u);
    return (unsigned short)(r >> 16);
}

// async global->LDS DMA, 16B per lane; dest = wave-uniform base + lane*16
__device__ __forceinline__ void load_lds16(const ushort* g, ushort* l) {
    __builtin_amdgcn_global_load_lds(
        (const __attribute__((address_space(1))) unsigned int*)g,
        (__attribute__((address_space(3))) unsigned int*)l,
        16, 0, 0);
}

// ---------- transpose + cast both weight tensors: Wt[e][n][k] = W[e][k][n] ----------
__global__ __launch_bounds__(256) void k_transpose2(const float* __restrict__ W1,
                                                    const float* __restrict__ W2,
                                                    ushort* __restrict__ w1t,
                                                    ushort* __restrict__ w2t) {
    int ez = blockIdx.z;
    const float* W = (ez < 8 ? W1 : W2) + (size_t)(ez & 7) * DM * DM;
    ushort* Wt = (ez < 8 ? w1t : w2t) + (size_t)(ez & 7) * DM * DM;
    __shared__ float t[64][65];
    int kt = blockIdx.y * 64, nt = blockIdx.x * 64;
    int tid = threadIdx.x;
    int r16 = tid >> 4, c4 = (tid & 15) * 4;
#pragma unroll
    for (int p = 0; p < 4; p++) {
        int k = p * 16 + r16;
        float4 v = *(const float4*)&W[(size_t)(kt + k) * DM + nt + c4];
        t[k][c4] = v.x; t[k][c4 + 1] = v.y; t[k][c4 + 2] = v.z; t[k][c4 + 3] = v.w;
    }
    __syncthreads();
    int n = tid >> 2, kb = (tid & 3) * 16;
#pragma unroll
    for (int h = 0; h < 2; h++) {
        int k0 = kb + h * 8;
        u16x8 o;
#pragma unroll
        for (int i = 0; i < 8; i++) o[i] = f2bf(t[k0 + i][n]);
        *(u16x8*)&Wt[(size_t)(nt + n) * DM + kt + k0] = o;
    }
}

// ---------- gating: scores = x@Wg + bg (fp32 exact), top-2, counts; also casts x->bf16 ----------
__global__ __launch_bounds__(256) void k_gate(const float* __restrict__ x,
                                              const float* __restrict__ Wg,
                                              const float* __restrict__ bg,
                                              ushort* __restrict__ xb,
                                              int* __restrict__ tok_e,
                                              float* __restrict__ tok_w,
                                              int* __restrict__ counts) {
    __shared__ float wgT[NE][DM];   // 32 KB, transposed: wgT[e][d] = Wg[d][e]
    __shared__ int cnt[NE];
    int tid = threadIdx.x;
    if (tid < NE) cnt[tid] = 0;
    for (int i = tid; i < DM * NE; i += 256) {
        int d = i >> 3, e = i & 7;
        wgT[e][d] = Wg[i];
    }
    __syncthreads();
    int wave = tid >> 6, lane = tid & 63;
    int n0 = (blockIdx.x * 4 + wave) * 4;
    const float4* xr[4];
#pragma unroll
    for (int t = 0; t < 4; t++) xr[t] = (const float4*)(x + (size_t)(n0 + t) * DM);

    float acc[4][NE];
#pragma unroll
    for (int t = 0; t < 4; t++)
#pragma unroll
        for (int e = 0; e < NE; e++) acc[t][e] = 0.f;

#pragma unroll
    for (int j = 0; j < 4; j++) {
        float4 xv[4];
#pragma unroll
        for (int t = 0; t < 4; t++) xv[t] = xr[t][j * 64 + lane];
#pragma unroll
        for (int t = 0; t < 4; t++) {
            ushort4 o;
            o.x = f2bf(xv[t].x); o.y = f2bf(xv[t].y);
            o.z = f2bf(xv[t].z); o.w = f2bf(xv[t].w);
            ((ushort4*)xb)[(size_t)(n0 + t) * (DM / 4) + j * 64 + lane] = o;
        }
#pragma unroll
        for (int e = 0; e < NE; e++) {
            float4 wv = ((const float4*)&wgT[e][0])[j * 64 + lane];
#pragma unroll
            for (int t = 0; t < 4; t++) {
                acc[t][e] += xv[t].x * wv.x + xv[t].y * wv.y
                           + xv[t].z * wv.z + xv[t].w * wv.w;
            }
        }
    }
#pragma unroll
    for (int t = 0; t < 4; t++)
#pragma unroll
        for (int e = 0; e < NE; e++) {
#pragma unroll
            for (int off = 32; off >= 1; off >>= 1)
                acc[t][e] += __shfl_xor(acc[t][e], off);
        }
    if (lane < 4) {
        int t = lane, n = n0 + t;
        float sc[NE];
#pragma unroll
        for (int e = 0; e < NE; e++) sc[e] = acc[t][e] + bg[e];
        int e0 = 0; float v0 = sc[0];
#pragma unroll
        for (int e = 1; e < NE; e++) if (sc[e] > v0) { v0 = sc[e]; e0 = e; }
        int e1 = -1; float v1 = -3.0e38f;
#pragma unroll
        for (int e = 0; e < NE; e++) if (e != e0 && sc[e] > v1) { v1 = sc[e]; e1 = e; }
        tok_e[2 * n] = e0;     tok_w[2 * n] = v0;
        tok_e[2 * n + 1] = e1; tok_w[2 * n + 1] = v1;
        atomicAdd(&cnt[e0], 1);
        atomicAdd(&cnt[e1], 1);
    }
    __syncthreads();
    if (tid < NE) atomicAdd(&counts[tid], cnt[tid]);
}

// ---------- plan: padded bases + tile tables (serial, trivial) ----------
__global__ void k_plan(const int* __restrict__ counts, int* __restrict__ base,
                       int* __restrict__ cursor, int* __restrict__ tile_e,
                       int* __restrict__ tile_b, int* __restrict__ ntiles) {
    if (threadIdx.x == 0 && blockIdx.x == 0) {
        int off = 0, t = 0;
        for (int e = 0; e < NE; e++) {
            base[e] = off; cursor[e] = 0;
            int nt = (counts[e] + BM - 1) / BM;
            for (int i = 0; i < nt; i++) { tile_e[t] = e; tile_b[t] = off + i * BM; t++; }
            off += nt * BM;
        }
        *ntiles = t;
    }
}

// ---------- fill: scatter (token, weight) into expert slot ranges ----------
__global__ __launch_bounds__(256) void k_fill(const int* __restrict__ tok_e,
                                              const float* __restrict__ tok_w,
                                              const int* __restrict__ base,
                                              int* __restrict__ cursor,
                                              int* __restrict__ slot_token,
                                              float* __restrict__ slot_w) {
    int n = blockIdx.x * 256 + threadIdx.x;
#pragma unroll
    for (int k = 0; k < 2; k++) {
        int e = tok_e[2 * n + k];
        float w = tok_w[2 * n + k];
        int pos = atomicAdd(&cursor[e], 1);
        int s = base[e] + pos;
        slot_token[s] = n;
        slot_w[s] = w;
    }
}

// ---------- grouped GEMM: 128x128 tile, BK=32, 3-buffer async pipeline ----------
// LDS per (buf, operand): [row 0..127][4 seg][8 ushort] = 8 KB; 3 bufs -> 48 KB total.
// DMA chunk = 16 rows x 64B: lane l -> row c*16+(l>>2), LDS seg l&3,
//   GLOBAL seg gseg = (l&3) ^ ((l>>4)&3)  [xor swizzle; dest stays uniform + l*16].
// Element (row, k=g*8+i) at seg_pos = g ^ ((row>>2)&3); fragment-read sel collapses
// to lane-constant quad ^ (lm>>2) -> conflict-free ds_read_b128.
// Pipeline (depth 2): at iter it issue buf (it+2)%3, s_waitcnt vmcnt(8) -> only the
// oldest 4 (= current buf) must land; 8 newer DMAs stay in flight across barriers.
// FENCES (R6): sched_barrier(0) pins ds_read/MFMA strictly between the barriers;
// lgkmcnt(0) before the end barrier guarantees ds_reads retired before republish.
// Grid is 1-D, XCD-swizzled: XCD j gets tiles [17j, 17j+17) x all 8 col-tiles, i.e.
// ~one expert -> its 2MB weight panel + A rows are L2-resident on that XCD.
template <int PHASE>
__global__ __launch_bounds__(256) void k_gemm(const ushort* __restrict__ A,
                                              const ushort* __restrict__ Wt,
                                              const float* __restrict__ bias,
                                              const int* __restrict__ slot_token,
                                              const float* __restrict__ slot_w,
                                              const int* __restrict__ tile_e,
                                              const int* __restrict__ tile_b,
                                              const int* __restrict__ ntiles,
                                              ushort* __restrict__ Hout,
                                              float* __restrict__ out) {
    // XCD-aware swizzle: nblocks = 8*MAXTILES (divisible by 8); chunk = MAXTILES.
    int flat = blockIdx.x;
    int wid = (flat & 7) * MAXTILES + (flat >> 3);
    int t = wid >> 3;
    if (t >= *ntiles) return;
    int ncol0 = (wid & 7) << 7;
    int e = tile_e[t];
    int sbase = tile_b[t];

    __shared__ ushort As[3][4096];   // [buf][row*32 + segpos*8]
    __shared__ ushort Bs[3][4096];

    int tid = threadIdx.x;
    int wave = tid >> 6, lane = tid & 63, quad = lane >> 4, lm = lane & 15;
    int wm = wave >> 1, wn = wave & 1;

    const ushort* Wte = Wt + (size_t)e * DM * DM;

    // staging: wave w covers chunks {2w, 2w+1} per operand (16 rows each)
    int sr = lane >> 2;                            // row-in-chunk 0..15
    int gseg = (lane & 3) ^ ((lane >> 4) & 3);     // global 16B-seg (xor swizzle)
    const ushort* aptr[2];
    const ushort* bptr[2];
#pragma unroll
    for (int ci = 0; ci < 2; ci++) {
        int row = (wave * 2 + ci) * 16 + sr;
        int ar;
        if (PHASE == 1) {
            ar = slot_token[sbase + row];
            if (ar < 0) ar = 0;              // pad rows: load row 0, discard in epilogue
        } else {
            ar = sbase + row;
        }
        aptr[ci] = A + (size_t)ar * DM + gseg * 8;
        bptr[ci] = Wte + (size_t)(ncol0 + row) * DM + gseg * 8;
    }

    f32x4 acc[4][4];
#pragma unroll
    for (int i = 0; i < 4; i++)
#pragma unroll
        for (int j = 0; j < 4; j++) acc[i][j] = (f32x4){0.f, 0.f, 0.f, 0.f};

    // fragment LDS offsets (ushort units): lane-constant swizzle sel
    int asel = ((quad ^ (lm >> 2)) & 3) * 8;
    int abase = (wm * 64 + lm) * 32 + asel;
    int bbase = (wn * 64 + lm) * 32 + asel;

#define ISSUE(buf, koff)                                          \
    do {                                                          \
        _Pragma("unroll")                                         \
        for (int ci = 0; ci < 2; ci++) {                          \
            int cb = (wave * 2 + ci) * 512;                       \
            load_lds16(aptr[ci] + (koff), &As[(buf)][cb]);        \
            load_lds16(bptr[ci] + (koff), &Bs[(buf)][cb]);        \
        }                                                         \
    } while (0)

#define COMPUTE(buf)                                                          \
    do {                                                                      \
        const ushort* Ab = As[(buf)];                                         \
        const ushort* Bb = Bs[(buf)];                                         \
        bf16x8 av[4], bv[4];                                                  \
        _Pragma("unroll")                                                     \
        for (int f = 0; f < 4; f++) {                                         \
            av[f] = *(const bf16x8*)&Ab[abase + f * 512];                     \
            bv[f] = *(const bf16x8*)&Bb[bbase + f * 512];                     \
        }                                                                     \
        _Pragma("unroll")                                                     \
        for (int fm = 0; fm < 4; fm++)                                        \
            _Pragma("unroll")                                                 \
            for (int fn = 0; fn < 4; fn++)                                    \
                acc[fm][fn] = __builtin_amdgcn_mfma_f32_16x16x32_bf16(        \
                    av[fm], bv[fn], acc[fm][fn], 0, 0, 0);                    \
    } while (0)

    // prologue: bufs 0 and 1 in flight (8 outstanding DMAs/wave)
    ISSUE(0, 0);
    ISSUE(1, 32);
#pragma unroll 3
    for (int it = 0; it < 30; ++it) {
        ISSUE((it + 2) % 3, (it + 2) * 32);       // 12 outstanding
        __builtin_amdgcn_s_waitcnt(0x0F78);       // vmcnt(8): current buf landed
        __builtin_amdgcn_s_barrier();
        __builtin_amdgcn_sched_barrier(0);        // ds_reads may not hoist above
        COMPUTE(it % 3);
        __builtin_amdgcn_sched_barrier(0);        // MFMAs/ds_reads may not sink below
        __builtin_amdgcn_s_waitcnt(0xC07F);       // lgkmcnt(0): ds_reads retired
        __builtin_amdgcn_s_barrier();             // readers done before buf re-staged
    }
    // it = 30: bufs 30,31 outstanding
    __builtin_amdgcn_s_waitcnt(0x0F74);           // vmcnt(4): buf 30 landed
    __builtin_amdgcn_s_barrier();
    __builtin_amdgcn_sched_barrier(0);
    COMPUTE(0);                                   // 30 % 3
    __builtin_amdgcn_sched_barrier(0);
    __builtin_amdgcn_s_waitcnt(0xC07F);
    __builtin_amdgcn_s_barrier();
    // it = 31
    __builtin_amdgcn_s_waitcnt(0x0F70);           // vmcnt(0): buf 31 landed
    __builtin_amdgcn_s_barrier();
    __builtin_amdgcn_sched_barrier(0);
    COMPUTE(1);                                   // 31 % 3
#undef ISSUE
#undef COMPUTE

    // epilogue — C/D layout: col = lane&15, row = quad*4 + r  [m89-verified]
#pragma unroll
    for (int fm = 0; fm < 4; fm++) {
        int rowg = wm * 64 + fm * 16 + quad * 4;
        if (PHASE == 1) {
#pragma unroll
            for (int fn = 0; fn < 4; fn++) {
                int col = ncol0 + wn * 64 + fn * 16 + lm;
                float bv2 = bias[e * DM + col];
#pragma unroll
                for (int r = 0; r < 4; r++) {
                    float v = acc[fm][fn][r] + bv2;
                    v = fmaxf(v, 0.f);
                    Hout[(size_t)(sbase + rowg + r) * DM + col] = f2bf(v);
                }
            }
        } else {
            int tk[4]; float wv[4];
#pragma unroll
            for (int r = 0; r < 4; r++) {
                tk[r] = slot_token[sbase + rowg + r];
                wv[r] = slot_w[sbase + rowg + r];
            }
#pragma unroll
            for (int fn = 0; fn < 4; fn++) {
                int col = ncol0 + wn * 64 + fn * 16 + lm;
                float bv2 = bias[e * DM + col];
#pragma unroll
                for (int r = 0; r < 4; r++) {
                    if (tk[r] >= 0) {
                        float v = wv[r] * (acc[fm][fn][r] + bv2);
                        atomicAdd(&out[(size_t)tk[r] * DM + col], v);
                    }
                }
            }
        }
    }
}

extern "C" void kernel_launch(void* const* d_in, const int* in_sizes, int n_in,
                              void* d_out, int out_size, void* d_ws, size_t ws_size,
                              hipStream_t stream) {
    const float* x  = (const float*)d_in[0];
    const float* Wg = (const float*)d_in[1];
    const float* bg = (const float*)d_in[2];
    const float* W1 = (const float*)d_in[3];
    const float* b1 = (const float*)d_in[4];
    const float* W2 = (const float*)d_in[5];
    const float* b2 = (const float*)d_in[6];
    float* out = (float*)d_out;

    char* ws = (char*)d_ws;
    // workspace layout (bytes) — total ~86.3 MB
    ushort* xb         = (ushort*)(ws + 0);            // 16 MB
    ushort* w1t        = (ushort*)(ws + 16777216);     // 16 MB
    ushort* w2t        = (ushort*)(ws + 33554432);     // 16 MB
    ushort* H          = (ushort*)(ws + 50331648);     // 34 MB (PADCAP*DM*2)
    int*    tok_e      = (int*)  (ws + 85983232);
    float*  tok_w      = (float*)(ws + 86048768);
    int*    slot_token = (int*)  (ws + 86114304);
    float*  slot_w     = (float*)(ws + 86183936);
    int*    counts     = (int*)  (ws + 86253568);
    int*    cursor     = counts + 8;
    int*    base       = counts + 16;
    int*    tile_e     = counts + 24;
    int*    tile_b     = tile_e + MAXTILES;
    int*    ntiles     = tile_b + MAXTILES;

    hipMemsetAsync(counts, 0, 16 * sizeof(int), stream);              // counts + cursor
    hipMemsetAsync(slot_token, 0xFF, PADCAP * sizeof(int), stream);   // -1 sentinels
    hipMemsetAsync(out, 0, (size_t)NTOK * DM * sizeof(float), stream);

    dim3 tg(16, 16, 16);
    k_transpose2<<<tg, 256, 0, stream>>>(W1, W2, w1t, w2t);
    k_gate<<<NTOK / 16, 256, 0, stream>>>(x, Wg, bg, xb, tok_e, tok_w, counts);
    k_plan<<<1, 64, 0, stream>>>(counts, base, cursor, tile_e, tile_b, ntiles);
    k_fill<<<NTOK / 256, 256, 0, stream>>>(tok_e, tok_w, base, cursor, slot_token, slot_w);

    dim3 gg(8 * MAXTILES);   // 1-D, XCD-swizzled in-kernel
    k_gemm<1><<<gg, 256, 0, stream>>>(xb, w1t, b1, slot_token, slot_w,
                                      tile_e, tile_b, ntiles, H, nullptr);
    k_gemm<2><<<gg, 256, 0, stream>>>(H, w2t, b2, slot_token, slot_w,
                                      tile_e, tile_b, ntiles, nullptr, out);
}

// Round 3
// 404.023 us; speedup vs baseline: 1.0889x; 1.0396x over previous
//
#include <hip/hip_runtime.h>
#include <hip/hip_bf16.h>

// MoE top-2, d=1024, E=8, N=8192 tokens. Grouped-GEMM design:
//   gate(top2 + x->bf16 cast + out/slot zero) -> fillplan -> GEMM1(relu) -> GEMM2(+atomic combine)
// R4: BK=32 dbuf + raw barrier/vmcnt. R5: depth-2 pipeline FAILED (sched reorder race).
// R6: fences fixed it; XCD swizzle cut FETCH 145->35MB but time ~flat -> NOT mem-latency
//     bound: per-iter fixed overhead (2 barriers + lgkm drain) x32 dominates (~4000cyc/slot
//     vs ~155cyc MFMA).
// R7: (a) BK=64: 16 iters instead of 32 -> overhead paid half as often; 2 bufs x 32KB
//         (64KB LDS, 2 blocks/CU); 8-seg XOR swizzle (2-way conflicts = free);
//         vmcnt(8) counted wait; same R6 fence discipline; + setprio around MFMAs.
//     (b) launch-count 10 -> 5: memsets folded into k_transpose2/k_gate; k_plan merged
//         into k_fill (per-thread local base recompute; block 0 writes tile tables).

#define NTOK   8192
#define DM     1024
#define NE     8
#define BM     128
#define NSLOT  (NTOK * 2)
#define PADCAP (NSLOT + NE * BM)      // 17408
#define MAXTILES (PADCAP / BM)        // 136

typedef __attribute__((ext_vector_type(8))) short  bf16x8;
typedef __attribute__((ext_vector_type(4))) float  f32x4;
typedef __attribute__((ext_vector_type(8))) unsigned short u16x8;

__device__ __forceinline__ unsigned short f2bf(float f) {
    union { float f; unsigned u; } v; v.f = f;
    unsigned r = v.u + 0x7fffu + ((v.u >> 16) & 1u);
    return (unsigned short)(r >> 16);
}

// async global->LDS DMA, 16B per lane; dest = wave-uniform base + lane*16
__device__ __forceinline__ void load_lds16(const ushort* g, ushort* l) {
    __builtin_amdgcn_global_load_lds(
        (const __attribute__((address_space(1))) unsigned int*)g,
        (__attribute__((address_space(3))) unsigned int*)l,
        16, 0, 0);
}

// ---------- transpose + cast both weight tensors: Wt[e][n][k] = W[e][k][n] ----------
// Also zeroes counts/cursor (runs first on the stream; k_gate depends on it).
__global__ __launch_bounds__(256) void k_transpose2(const float* __restrict__ W1,
                                                    const float* __restrict__ W2,
                                                    ushort* __restrict__ w1t,
                                                    ushort* __restrict__ w2t,
                                                    int* __restrict__ counts) {
    int tid = threadIdx.x;
    if (blockIdx.x == 0 && blockIdx.y == 0 && blockIdx.z == 0 && tid < 16)
        counts[tid] = 0;   // counts[0..7] + cursor[0..7]
    int ez = blockIdx.z;
    const float* W = (ez < 8 ? W1 : W2) + (size_t)(ez & 7) * DM * DM;
    ushort* Wt = (ez < 8 ? w1t : w2t) + (size_t)(ez & 7) * DM * DM;
    __shared__ float t[64][65];
    int kt = blockIdx.y * 64, nt = blockIdx.x * 64;
    int r16 = tid >> 4, c4 = (tid & 15) * 4;
#pragma unroll
    for (int p = 0; p < 4; p++) {
        int k = p * 16 + r16;
        float4 v = *(const float4*)&W[(size_t)(kt + k) * DM + nt + c4];
        t[k][c4] = v.x; t[k][c4 + 1] = v.y; t[k][c4 + 2] = v.z; t[k][c4 + 3] = v.w;
    }
    __syncthreads();
    int n = tid >> 2, kb = (tid & 3) * 16;
#pragma unroll
    for (int h = 0; h < 2; h++) {
        int k0 = kb + h * 8;
        u16x8 o;
#pragma unroll
        for (int i = 0; i < 8; i++) o[i] = f2bf(t[k0 + i][n]);
        *(u16x8*)&Wt[(size_t)(nt + n) * DM + kt + k0] = o;
    }
}

// ---------- gating: scores = x@Wg + bg (fp32 exact), top-2, counts; casts x->bf16 ----------
// Also zeroes its 16 output rows and its slot_token chunk (replaces 2 memset launches).
__global__ __launch_bounds__(256) void k_gate(const float* __restrict__ x,
                                              const float* __restrict__ Wg,
                                              const float* __restrict__ bg,
                                              ushort* __restrict__ xb,
                                              int* __restrict__ tok_e,
                                              float* __restrict__ tok_w,
                                              int* __restrict__ counts,
                                              float* __restrict__ out,
                                              int* __restrict__ slot_token) {
    __shared__ float wgT[NE][DM];   // 32 KB, transposed: wgT[e][d] = Wg[d][e]
    __shared__ int cnt[NE];
    int tid = threadIdx.x;
    if (tid < NE) cnt[tid] = 0;
    // zero out rows [16*blk, 16*blk+16): 4096 float4 across 256 threads
    {
        float4 z4 = {0.f, 0.f, 0.f, 0.f};
        float4* orow = (float4*)(out + (size_t)blockIdx.x * 16 * DM);
#pragma unroll
        for (int i = 0; i < 16; i++) orow[i * 256 + tid] = z4;
        // slot_token sentinels: PADCAP = 512 blocks * 34
        int s0 = blockIdx.x * 34;
        for (int i = tid; i < 34; i += 256) slot_token[s0 + i] = -1;
    }
    for (int i = tid; i < DM * NE; i += 256) {
        int d = i >> 3, e = i & 7;
        wgT[e][d] = Wg[i];
    }
    __syncthreads();
    int wave = tid >> 6, lane = tid & 63;
    int n0 = (blockIdx.x * 4 + wave) * 4;
    const float4* xr[4];
#pragma unroll
    for (int t = 0; t < 4; t++) xr[t] = (const float4*)(x + (size_t)(n0 + t) * DM);

    float acc[4][NE];
#pragma unroll
    for (int t = 0; t < 4; t++)
#pragma unroll
        for (int e = 0; e < NE; e++) acc[t][e] = 0.f;

#pragma unroll
    for (int j = 0; j < 4; j++) {
        float4 xv[4];
#pragma unroll
        for (int t = 0; t < 4; t++) xv[t] = xr[t][j * 64 + lane];
#pragma unroll
        for (int t = 0; t < 4; t++) {
            ushort4 o;
            o.x = f2bf(xv[t].x); o.y = f2bf(xv[t].y);
            o.z = f2bf(xv[t].z); o.w = f2bf(xv[t].w);
            ((ushort4*)xb)[(size_t)(n0 + t) * (DM / 4) + j * 64 + lane] = o;
        }
#pragma unroll
        for (int e = 0; e < NE; e++) {
            float4 wv = ((const float4*)&wgT[e][0])[j * 64 + lane];
#pragma unroll
            for (int t = 0; t < 4; t++) {
                acc[t][e] += xv[t].x * wv.x + xv[t].y * wv.y
                           + xv[t].z * wv.z + xv[t].w * wv.w;
            }
        }
    }
#pragma unroll
    for (int t = 0; t < 4; t++)
#pragma unroll
        for (int e = 0; e < NE; e++) {
#pragma unroll
            for (int off = 32; off >= 1; off >>= 1)
                acc[t][e] += __shfl_xor(acc[t][e], off);
        }
    if (lane < 4) {
        int t = lane, n = n0 + t;
        float sc[NE];
#pragma unroll
        for (int e = 0; e < NE; e++) sc[e] = acc[t][e] + bg[e];
        int e0 = 0; float v0 = sc[0];
#pragma unroll
        for (int e = 1; e < NE; e++) if (sc[e] > v0) { v0 = sc[e]; e0 = e; }
        int e1 = -1; float v1 = -3.0e38f;
#pragma unroll
        for (int e = 0; e < NE; e++) if (e != e0 && sc[e] > v1) { v1 = sc[e]; e1 = e; }
        tok_e[2 * n] = e0;     tok_w[2 * n] = v0;
        tok_e[2 * n + 1] = e1; tok_w[2 * n + 1] = v1;
        atomicAdd(&cnt[e0], 1);
        atomicAdd(&cnt[e1], 1);
    }
    __syncthreads();
    if (tid < NE) atomicAdd(&counts[tid], cnt[tid]);
}

// ---------- fill + plan merged: per-thread local base; block 0 writes tile tables ----------
__global__ __launch_bounds__(256) void k_fillplan(const int* __restrict__ tok_e,
                                                  const float* __restrict__ tok_w,
                                                  const int* __restrict__ counts,
                                                  int* __restrict__ cursor,
                                                  int* __restrict__ slot_token,
                                                  float* __restrict__ slot_w,
                                                  int* __restrict__ tile_e,
                                                  int* __restrict__ tile_b,
                                                  int* __restrict__ ntiles) {
    int tid = threadIdx.x;
    int cnts[NE];
#pragma unroll
    for (int e = 0; e < NE; e++) cnts[e] = counts[e];
    int base[NE]; int off = 0;
#pragma unroll
    for (int e = 0; e < NE; e++) {
        base[e] = off;
        off += ((cnts[e] + BM - 1) / BM) * BM;
    }
    if (blockIdx.x == 0 && tid == 0) {
        int t = 0, o2 = 0;
        for (int e = 0; e < NE; e++) {
            int nt = (cnts[e] + BM - 1) / BM;
            for (int i = 0; i < nt; i++) { tile_e[t] = e; tile_b[t] = o2 + i * BM; t++; }
            o2 += nt * BM;
        }
        *ntiles = t;
    }
    int n = blockIdx.x * 256 + tid;
#pragma unroll
    for (int k = 0; k < 2; k++) {
        int e = tok_e[2 * n + k];
        float w = tok_w[2 * n + k];
        int pos = atomicAdd(&cursor[e], 1);
        int s = base[e] + pos;
        slot_token[s] = n;
        slot_w[s] = w;
    }
}

// ---------- grouped GEMM: 128x128 tile, BK=64, double-buffered async pipeline ----------
// LDS per (buf, operand): [row 0..127][8 seg][8 ushort] = 16 KB; total 64 KB (2 blocks/CU).
// DMA chunk = 8 rows x 128B: lane l -> row l>>3, LDS seg l&7,
//   GLOBAL seg gseg = (l&7) ^ (l>>3)   [xor swizzle keyed on row&7; dest uniform + l*16].
// Element (row, k = g*8+i) stored at seg g ^ (row&7); fragment-read sel = (ks*4+quad)
//   ^ (lm&7): lanes lm 0..7 hit 8 distinct 16B slots -> 2 rows/slot -> 2-way (free, m136).
// Pipeline: prefetch next buf (8 DMAs/wave), s_waitcnt vmcnt(8) = current buf's 8 landed
// (8 newer stay in flight across barriers). Fences per R6: sched_barrier(0) at region
// boundaries + lgkmcnt(0) before the end barrier. setprio(1) around the MFMA cluster.
// Grid 1-D XCD-swizzled: XCD j gets tiles [17j,17j+17) x 8 col-tiles (~one expert -> L2).
template <int PHASE>
__global__ __launch_bounds__(256) void k_gemm(const ushort* __restrict__ A,
                                              const ushort* __restrict__ Wt,
                                              const float* __restrict__ bias,
                                              const int* __restrict__ slot_token,
                                              const float* __restrict__ slot_w,
                                              const int* __restrict__ tile_e,
                                              const int* __restrict__ tile_b,
                                              const int* __restrict__ ntiles,
                                              ushort* __restrict__ Hout,
                                              float* __restrict__ out) {
    int flat = blockIdx.x;
    int wid = (flat & 7) * MAXTILES + (flat >> 3);
    int t = wid >> 3;
    if (t >= *ntiles) return;
    int ncol0 = (wid & 7) << 7;
    int e = tile_e[t];
    int sbase = tile_b[t];

    __shared__ ushort As[2][8192];   // [buf][row*64 + seg*8]
    __shared__ ushort Bs[2][8192];

    int tid = threadIdx.x;
    int wave = tid >> 6, lane = tid & 63, quad = lane >> 4, lm = lane & 15;
    int wm = wave >> 1, wn = wave & 1;

    const ushort* Wte = Wt + (size_t)e * DM * DM;

    // staging: wave w covers rows [32w, 32w+32) in 4 chunks of 8 rows per operand
    int sr = lane >> 3;                 // row-in-chunk 0..7
    int gseg = (lane & 7) ^ sr;         // global 16B-seg (xor swizzle, keyed on row&7)
    const ushort* aptr[4];
    const ushort* bptr[4];
#pragma unroll
    for (int ci = 0; ci < 4; ci++) {
        int row = wave * 32 + ci * 8 + sr;
        int ar;
        if (PHASE == 1) {
            ar = slot_token[sbase + row];
            if (ar < 0) ar = 0;              // pad rows: load row 0, discard in epilogue
        } else {
            ar = sbase + row;
        }
        aptr[ci] = A + (size_t)ar * DM + gseg * 8;
        bptr[ci] = Wte + (size_t)(ncol0 + row) * DM + gseg * 8;
    }

    f32x4 acc[4][4];
#pragma unroll
    for (int i = 0; i < 4; i++)
#pragma unroll
        for (int j = 0; j < 4; j++) acc[i][j] = (f32x4){0.f, 0.f, 0.f, 0.f};

    // fragment LDS offsets (ushort units): abase includes ks=0 seg-sel; ks=1 = XOR 32
    int asel = (quad ^ (lm & 7)) * 8;
    int abase = (wm * 64 + lm) * 64 + asel;
    int bbase = (wn * 64 + lm) * 64 + asel;

#define ISSUE(buf, koff)                                          \
    do {                                                          \
        _Pragma("unroll")                                         \
        for (int ci = 0; ci < 4; ci++)                            \
            load_lds16(aptr[ci] + (koff), &As[(buf)][(wave * 32 + ci * 8) * 64]); \
        _Pragma("unroll")                                         \
        for (int ci = 0; ci < 4; ci++)                            \
            load_lds16(bptr[ci] + (koff), &Bs[(buf)][(wave * 32 + ci * 8) * 64]); \
    } while (0)

#define COMPUTE(buf)                                                          \
    do {                                                                      \
        const ushort* Ab = As[(buf)];                                         \
        const ushort* Bb = Bs[(buf)];                                         \
        bf16x8 av0[4], bv0[4], av1[4], bv1[4];                                \
        _Pragma("unroll")                                                     \
        for (int f = 0; f < 4; f++) {                                         \
            av0[f] = *(const bf16x8*)&Ab[abase + f * 1024];                   \
            bv0[f] = *(const bf16x8*)&Bb[bbase + f * 1024];                   \
        }                                                                     \
        _Pragma("unroll")                                                     \
        for (int f = 0; f < 4; f++) {                                         \
            av1[f] = *(const bf16x8*)&Ab[(abase + f * 1024) ^ 32];            \
            bv1[f] = *(const bf16x8*)&Bb[(bbase + f * 1024) ^ 32];            \
        }                                                                     \
        __builtin_amdgcn_s_setprio(1);                                        \
        _Pragma("unroll")                                                     \
        for (int fm = 0; fm < 4; fm++)                                        \
            _Pragma("unroll")                                                 \
            for (int fn = 0; fn < 4; fn++)                                    \
                acc[fm][fn] = __builtin_amdgcn_mfma_f32_16x16x32_bf16(        \
                    av0[fm], bv0[fn], acc[fm][fn], 0, 0, 0);                  \
        _Pragma("unroll")                                                     \
        for (int fm = 0; fm < 4; fm++)                                        \
            _Pragma("unroll")                                                 \
            for (int fn = 0; fn < 4; fn++)                                    \
                acc[fm][fn] = __builtin_amdgcn_mfma_f32_16x16x32_bf16(        \
                    av1[fm], bv1[fn], acc[fm][fn], 0, 0, 0);                  \
        __builtin_amdgcn_s_setprio(0);                                        \
    } while (0)

    // prologue: buf 0 in flight (8 outstanding DMAs/wave)
    ISSUE(0, 0);
#pragma unroll 1
    for (int it = 0; it < 15; ++it) {
        ISSUE((it + 1) & 1, (it + 1) * 64);       // 16 outstanding
        __builtin_amdgcn_s_waitcnt(0x0F78);       // vmcnt(8): current buf's 8 landed
        __builtin_amdgcn_s_barrier();
        __builtin_amdgcn_sched_barrier(0);        // ds_reads may not hoist above
        COMPUTE(it & 1);
        __builtin_amdgcn_sched_barrier(0);        // nothing sinks below
        __builtin_amdgcn_s_waitcnt(0xC07F);       // lgkmcnt(0): ds_reads retired
        __builtin_amdgcn_s_barrier();             // readers done before buf re-staged
    }
    // it = 15 (buf 1), nothing left to prefetch
    __builtin_amdgcn_s_waitcnt(0x0F70);           // vmcnt(0)
    __builtin_amdgcn_s_barrier();
    __builtin_amdgcn_sched_barrier(0);
    COMPUTE(1);
#undef ISSUE
#undef COMPUTE

    // epilogue — C/D layout: col = lane&15, row = quad*4 + r  [m89-verified]
#pragma unroll
    for (int fm = 0; fm < 4; fm++) {
        int rowg = wm * 64 + fm * 16 + quad * 4;
        if (PHASE == 1) {
#pragma unroll
            for (int fn = 0; fn < 4; fn++) {
                int col = ncol0 + wn * 64 + fn * 16 + lm;
                float bv2 = bias[e * DM + col];
#pragma unroll
                for (int r = 0; r < 4; r++) {
                    float v = acc[fm][fn][r] + bv2;
                    v = fmaxf(v, 0.f);
                    Hout[(size_t)(sbase + rowg + r) * DM + col] = f2bf(v);
                }
            }
        } else {
            int tk[4]; float wv[4];
#pragma unroll
            for (int r = 0; r < 4; r++) {
                tk[r] = slot_token[sbase + rowg + r];
                wv[r] = slot_w[sbase + rowg + r];
            }
#pragma unroll
            for (int fn = 0; fn < 4; fn++) {
                int col = ncol0 + wn * 64 + fn * 16 + lm;
                float bv2 = bias[e * DM + col];
#pragma unroll
                for (int r = 0; r < 4; r++) {
                    if (tk[r] >= 0) {
                        float v = wv[r] * (acc[fm][fn][r] + bv2);
                        atomicAdd(&out[(size_t)tk[r] * DM + col], v);
                    }
                }
            }
        }
    }
}

extern "C" void kernel_launch(void* const* d_in, const int* in_sizes, int n_in,
                              void* d_out, int out_size, void* d_ws, size_t ws_size,
                              hipStream_t stream) {
    const float* x  = (const float*)d_in[0];
    const float* Wg = (const float*)d_in[1];
    const float* bg = (const float*)d_in[2];
    const float* W1 = (const float*)d_in[3];
    const float* b1 = (const float*)d_in[4];
    const float* W2 = (const float*)d_in[5];
    const float* b2 = (const float*)d_in[6];
    float* out = (float*)d_out;

    char* ws = (char*)d_ws;
    // workspace layout (bytes) — total ~86.3 MB
    ushort* xb         = (ushort*)(ws + 0);            // 16 MB
    ushort* w1t        = (ushort*)(ws + 16777216);     // 16 MB
    ushort* w2t        = (ushort*)(ws + 33554432);     // 16 MB
    ushort* H          = (ushort*)(ws + 50331648);     // 34 MB (PADCAP*DM*2)
    int*    tok_e      = (int*)  (ws + 85983232);
    float*  tok_w      = (float*)(ws + 86048768);
    int*    slot_token = (int*)  (ws + 86114304);
    float*  slot_w     = (float*)(ws + 86183936);
    int*    counts     = (int*)  (ws + 86253568);
    int*    cursor     = counts + 8;
    int*    tile_e     = counts + 24;
    int*    tile_b     = tile_e + MAXTILES;
    int*    ntiles     = tile_b + MAXTILES;

    dim3 tg(16, 16, 16);
    k_transpose2<<<tg, 256, 0, stream>>>(W1, W2, w1t, w2t, counts);
    k_gate<<<NTOK / 16, 256, 0, stream>>>(x, Wg, bg, xb, tok_e, tok_w, counts,
                                          out, slot_token);
    k_fillplan<<<NTOK / 256, 256, 0, stream>>>(tok_e, tok_w, counts, cursor,
                                               slot_token, slot_w,
                                               tile_e, tile_b, ntiles);

    dim3 gg(8 * MAXTILES);   // 1-D, XCD-swizzled in-kernel
    k_gemm<1><<<gg, 256, 0, stream>>>(xb, w1t, b1, slot_token, slot_w,
                                      tile_e, tile_b, ntiles, H, nullptr);
    k_gemm<2><<<gg, 256, 0, stream>>>(H, w2t, b2, slot_token, slot_w,
                                      tile_e, tile_b, ntiles, nullptr, out);
}